// Round 14
// baseline (171.350 us; speedup 1.0000x reference)
//
#include <hip/hip_runtime.h>

// SelfAttention: x[8,256,64,64] fp32, W[256,256] fp32.
// R14: R11/R13 structure (fp8-MX QK + bf16 PV, 2 blocks/CU) with a
// BALANCED V LDS layout (zero excess bank conflicts, derived):
//   byte(c, jc) = (c>>2)*256 + ((((jc<<2)|(c&3)) ^ ((c>>2)&15)) << 4)
// Every PV ds_read_b128 puts exactly 8 distinct 16B chunks on each of the
// 8 bank positions = hardware floor. PV read addrs collapse to 2 regs.
// 512 blocks = 8b x 32qt x 2 j-halves; 4 waves x 32 q-rows; JT=32.
// ws: xT8[b][N][C] fp8 | xC[b][C][N] bf16 | ctxP[2][b][N][C] | Wb | ML

typedef __attribute__((ext_vector_type(8))) short short8;
typedef __attribute__((ext_vector_type(4))) float floatx4;
typedef __attribute__((ext_vector_type(16))) float floatx16;
typedef __attribute__((ext_vector_type(4))) int intx4;
typedef __attribute__((ext_vector_type(8))) int intx8;

#define N_TOK 4096
#define C_DIM 256
#define JT 32
#define NT 64  // 2048 / JT per half

typedef const __attribute__((address_space(1))) unsigned int g_uint;
typedef __attribute__((address_space(3))) unsigned int lds_uint;

__device__ __forceinline__ void gll16(const void* g, void* l) {
  __builtin_amdgcn_global_load_lds((g_uint*)g, (lds_uint*)l, 16, 0, 0);
}

__device__ __forceinline__ unsigned short f2bf(float f) {
  unsigned int u = __builtin_bit_cast(unsigned int, f);
  u += 0x7fffu + ((u >> 16) & 1u);
  return (unsigned short)(u >> 16);
}
__device__ __forceinline__ float bf2f(unsigned short v) {
  return __builtin_bit_cast(float, (unsigned int)v << 16);
}
// f32 -> fp8 e4m3fn, RNE, flush-subnormal, clamp 448 (hand-rolled)
__device__ __forceinline__ unsigned char f2f8(float f) {
  unsigned u = __builtin_bit_cast(unsigned, f);
  unsigned sgn = (u >> 24) & 0x80u;
  unsigned a = u & 0x7fffffffu;
  if (a > 0x43e40000u) return (unsigned char)(sgn | 0x7e);  // >456 -> 448
  unsigned lsb = (a >> 20) & 1u;
  a += 0x0007ffffu + lsb;  // RNE at 3-bit mantissa
  int e = (int)(a >> 23) - 127;
  if (e < -6) return (unsigned char)sgn;  // flush tiny/subnormal
  if (e > 8) return (unsigned char)(sgn | 0x7e);
  unsigned m = (a >> 20) & 7u;
  return (unsigned char)(sgn | ((unsigned)(e + 7) << 3) | m);
}

__device__ __forceinline__ floatx16 mfma32(short8 a, short8 b, floatx16 c) {
  return __builtin_amdgcn_mfma_f32_32x32x16_bf16(a, b, c, 0, 0, 0);
}
__device__ __forceinline__ floatx4 mfma16(short8 a, short8 b, floatx4 c) {
  return __builtin_amdgcn_mfma_f32_16x16x32_bf16(a, b, c, 0, 0, 0);
}
__device__ __forceinline__ floatx16 mfma_qk(intx8 a, intx8 b, floatx16 c) {
  // fp8 e4m3 A/B (cbsz=0, blgp=0), unity block scales (E8M0 127 = 2^0)
  return __builtin_amdgcn_mfma_scale_f32_32x32x64_f8f6f4(
      a, b, c, 0, 0, 0, 0x7f7f7f7f, 0, 0x7f7f7f7f);
}
__device__ __forceinline__ unsigned cvtpk(float lo, float hi) {
  unsigned d;
  asm("v_cvt_pk_bf16_f32 %0, %1, %2" : "=v"(d) : "v"(lo), "v"(hi));
  return d;
}
__device__ __forceinline__ void swap32(unsigned& a, unsigned& b) {
  asm("v_permlane32_swap_b32 %0, %1" : "+v"(a), "+v"(b));
}

// ---- K1a: x[b][c][i] fp32 -> xT8[b][i][c] fp8 and xC[b][c][i] bf16 ----
__global__ __launch_bounds__(256) void transpose_conv(
    const float* __restrict__ x, unsigned char* __restrict__ xT8,
    unsigned short* __restrict__ xC) {
  __shared__ float tile[32][33];
  const int b = blockIdx.z;
  const int i0 = blockIdx.x * 32, c0 = blockIdx.y * 32;
  const int tx = threadIdx.x & 31, ty = threadIdx.x >> 5;
  const float* xb = x + (size_t)b * C_DIM * N_TOK;
#pragma unroll
  for (int p = 0; p < 4; ++p) {
    int c = c0 + ty + p * 8;
    float v = xb[(size_t)c * N_TOK + i0 + tx];
    tile[ty + p * 8][tx] = v;
    xC[((size_t)b * C_DIM + c) * N_TOK + i0 + tx] = f2bf(v);
  }
  __syncthreads();
#pragma unroll
  for (int p = 0; p < 4; ++p) {
    int i = i0 + ty + p * 8;
    xT8[((size_t)b * N_TOK + i) * C_DIM + c0 + tx] = f2f8(tile[tx][ty + p * 8]);
  }
}

// ---- K1b: W fp32 -> bf16 ----
__global__ __launch_bounds__(256) void wconv(const float* __restrict__ W,
                                             unsigned short* __restrict__ Wb) {
  int idx = blockIdx.x * 256 + threadIdx.x;
  Wb[idx] = f2bf(W[idx]);
}

// ---- K2: split-K flash attention. grid 512, 256 thr, 2 blocks/CU ----
// LDS buffer (24KB each, x2):
//   K fp8 [0,8KB): elem(j, c16=c/16) at j*256 + ((c16 ^ (j&15))<<4)
//   V bf16 [8KB,24KB): elem(c, jc=j/8) at
//       (c>>2)*256 + ((((jc<<2)|(c&3)) ^ ((c>>2)&15))<<4)   [balanced]
__global__ __launch_bounds__(256, 2) void attn_kernel(
    const unsigned char* __restrict__ xT8, const unsigned short* __restrict__ xC,
    unsigned short* __restrict__ ctxP, float2* __restrict__ MLd) {
  const int bid = blockIdx.x;
  const int b = bid & 7;           // batch == XCD -> L2 locality
  const int qt = (bid >> 3) & 31;  // q-tile (128 rows)
  const int g = bid >> 8;          // j-half
  const int tid = threadIdx.x;
  const int lane = tid & 63;
  const int wv = tid >> 6;
  const int l31 = lane & 31;
  const int h = lane >> 5;
  const unsigned char* xT8b = xT8 + (size_t)b * N_TOK * C_DIM;
  const unsigned short* xCb = xC + (size_t)b * N_TOK * C_DIM;
  const int qb = qt * 128 + wv * 32;

  __shared__ char lds[2][24576];

  // --- precomputed staging sources (inverse-swizzled, rule #21) ---
  // K: slots o = i*4096 + wv*1024 + lane*16 (i=0..1)
  //    j = i*16 + wv*4 + (lane>>4); c16 = (lane&15) ^ (j&15)
  const char* kSrc[2];
  {
    const char* base = (const char*)xT8b + (size_t)g * 2048 * 256;
#pragma unroll
    for (int i = 0; i < 2; ++i) {
      int j = i * 16 + wv * 4 + (lane >> 4);
      int c16 = (lane & 15) ^ (j & 15);
      kSrc[i] = base + (size_t)j * 256 + c16 * 16;
    }
  }
  // V: slots o = i*4096 + wv*1024 + lane*16 (i=0..3); region row R = o>>8,
  //    u = (lane&15) ^ (R&15); jc = u>>2; c = R*4 + (u&3)
  const char* vSrc[4];
  {
    const char* base = (const char*)xCb + (size_t)g * 4096;
#pragma unroll
    for (int i = 0; i < 4; ++i) {
      int R = i * 16 + wv * 4 + (lane >> 4);
      int u = (lane & 15) ^ (R & 15);
      int c = R * 4 + (u & 3);
      vSrc[i] = base + (size_t)c * 8192 + (u >> 2) * 16;
    }
  }
  auto STAGE_K = [&](int t, int sel) {
    char* Kd = lds[sel] + wv * 1024;
    size_t toff = (size_t)t * 8192;  // 32 rows * 256 B
#pragma unroll
    for (int i = 0; i < 2; ++i) gll16(kSrc[i] + toff, Kd + i * 4096);
  };
  auto STAGE_V = [&](int t, int sel) {
    char* Vd = lds[sel] + 8192 + wv * 1024;
    size_t toff = (size_t)t * 64;  // 32 j * 2 B within xC rows
#pragma unroll
    for (int i = 0; i < 4; ++i) gll16(vSrc[i] + toff, Vd + i * 4096);
  };

  // PV read offsets (2 regs): slot = ((jc<<2)|(c&3)) ^ ((c>>2)&15),
  // c = ct*32 + l31 -> byte = ct*2048 + (l31>>2)*256 + slot*16.
  // jc in {h, 2+h}; ct parity and jc-step BOTH flip byte bit7.
  const int oA = (l31 >> 2) * 256 + ((((h << 2) | (l31 & 3)) ^ (l31 >> 2)) << 4);
  const int oB = oA ^ 128;

  // Q fp8 B-fragments: row qb+l31, k-bytes c = ks*64 + h*32 + (0..31)
  intx8 q[4];
  {
    const unsigned char* qp = xT8b + (size_t)(qb + l31) * C_DIM + h * 32;
#pragma unroll
    for (int ks = 0; ks < 4; ++ks) {
      intx4 lo = *(const intx4*)(qp + ks * 64);
      intx4 hi = *(const intx4*)(qp + ks * 64 + 16);
      q[ks] = (intx8){lo.x, lo.y, lo.z, lo.w, hi.x, hi.y, hi.z, hi.w};
    }
  }

  floatx16 acc[8];
#pragma unroll
  for (int ct = 0; ct < 8; ++ct)
#pragma unroll
    for (int r = 0; r < 16; ++r) acc[ct][r] = 0.f;
  float m = -1e30f, lsum = 0.f;
  const float SC = 0.09016844005556021f;  // log2(e)/16

  STAGE_K(0, 0);
  STAGE_V(0, 0);

  for (int t = 0; t < NT; ++t) {
    __syncthreads();  // tile t staged (vmcnt drain); prev-buf reads done
    if (t + 1 < NT) {
      STAGE_K(t + 1, (t + 1) & 1);
      STAGE_V(t + 1, (t + 1) & 1);
    }
    const char* Kb = lds[t & 1];
    const char* Vb = lds[t & 1] + 8192;

    // S^T = mfma_scale(K8, Q8): A m=j=l31, B n=i=l31
    floatx16 s;
#pragma unroll
    for (int r = 0; r < 16; ++r) s[r] = 0.f;
    __builtin_amdgcn_s_setprio(1);
#pragma unroll
    for (int ks = 0; ks < 4; ++ks) {
      int ch = ((ks * 4 + h * 2) ^ (l31 & 15)) << 4;
      intx4 ka = *(const intx4*)(Kb + l31 * 256 + ch);
      intx4 kb2 = *(const intx4*)(Kb + l31 * 256 + (ch ^ 16));
      intx8 kf = (intx8){ka.x, ka.y, ka.z, ka.w, kb2.x, kb2.y, kb2.z, kb2.w};
      s = mfma_qk(kf, q[ks], s);
    }
    __builtin_amdgcn_s_setprio(0);

    // online softmax over 32 j (lane owns q-row i=l31; dup in h)
    float mx = s[0];
#pragma unroll
    for (int r = 1; r < 16; ++r) mx = fmaxf(mx, s[r]);
    mx = fmaxf(mx, __shfl_xor(mx, 32));
    float pm = mx * SC;
    bool need = __any(pm > m + 8.0f) != 0;  // defer-max (T13)
    float mn = need ? fmaxf(m, pm) : m;
    float al = need ? exp2f(m - mn) : 1.0f;
    m = mn;
    float rsum = 0.f;
#pragma unroll
    for (int r = 0; r < 16; ++r) {
      s[r] = exp2f(s[r] * SC - mn);
      rsum += s[r];
    }
    rsum += __shfl_xor(rsum, 32);
    lsum = lsum * al + rsum;
    if (need) {  // wave-uniform, rare after warmup
#pragma unroll
      for (int r = 0; r < 16; ++r) {
        float ar = __shfl(al, (r & 3) + 8 * (r >> 2) + 4 * h);
#pragma unroll
        for (int ct = 0; ct < 8; ++ct) acc[ct][r] *= ar;
      }
    }

    // P^T -> PV A-fragments in-register (cvt_pk + permlane32_swap), bf16
    unsigned pk[8];
#pragma unroll
    for (int pi = 0; pi < 8; ++pi) pk[pi] = cvtpk(s[2 * pi], s[2 * pi + 1]);
    swap32(pk[0], pk[2]); swap32(pk[1], pk[3]);
    swap32(pk[4], pk[6]); swap32(pk[5], pk[7]);
    intx4 a0v = {(int)pk[0], (int)pk[1], (int)pk[2], (int)pk[3]};
    intx4 a1v = {(int)pk[4], (int)pk[5], (int)pk[6], (int)pk[7]};
    short8 pa0 = __builtin_bit_cast(short8, a0v);  // k = j 0..15
    short8 pa1 = __builtin_bit_cast(short8, a1v);  // k = j 16..31

    // O[i][c] += P[i][j] V[j][c]; balanced layout, addrs = 2 regs + imm
    __builtin_amdgcn_s_setprio(1);
#pragma unroll
    for (int ct = 0; ct < 8; ++ct) {
      const char* vb0 = Vb + ct * 2048 + ((ct & 1) ? oB : oA);
      const char* vb1 = Vb + ct * 2048 + ((ct & 1) ? oA : oB);
      short8 v0 = *(const short8*)(vb0);
      short8 v1 = *(const short8*)(vb1);
      acc[ct] = mfma32(pa0, v0, acc[ct]);
      acc[ct] = mfma32(pa1, v1, acc[ct]);
    }
    __builtin_amdgcn_s_setprio(0);
  }

  // epilogue: store partial O (bf16, unnormalized) + (m, l)
  if (h == 0) {
    float2 ml; ml.x = m; ml.y = lsum;
    MLd[((size_t)g * 8 + b) * N_TOK + qb + l31] = ml;
  }
  unsigned short* cb = ctxP + (((size_t)g * 8 + b) * N_TOK + qb) * C_DIM;
#pragma unroll
  for (int r = 0; r < 16; ++r) {
    int ri = (r & 3) + 8 * (r >> 2) + 4 * h;
#pragma unroll
    for (int ct = 0; ct < 8; ++ct)
      cb[(size_t)ri * C_DIM + ct * 32 + l31] = f2bf(acc[ct][r]);
  }
}

// ---- K3: merge halves + out[b][o][i] = (1/l) sum_c W[o][c] ctx[i][c] ----
__global__ __launch_bounds__(256) void outgemm(
    const unsigned short* __restrict__ ctxP, const unsigned short* __restrict__ Wb,
    const float2* __restrict__ MLd, float* __restrict__ out) {
  const int bid = blockIdx.x;
  const int b = bid & 7;
  const int it = bid >> 3;
  const int lane = threadIdx.x & 63;
  const int w = threadIdx.x >> 6;
  const int ibase = it * 64 + w * 16;
  const int l15 = lane & 15, lhi = lane >> 4;
  const unsigned short* c0base = ctxP + (size_t)b * N_TOK * C_DIM;
  const unsigned short* c1base = ctxP + (size_t)(8 + b) * N_TOK * C_DIM;
  const float2* ml0b = MLd + (size_t)b * N_TOK;
  const float2* ml1b = MLd + (size_t)(8 + b) * N_TOK;

  // A-row merge weights (row ia = ibase + l15)
  const int ia = ibase + l15;
  float2 ma = ml0b[ia], mb = ml1b[ia];
  float Ma = fmaxf(ma.x, mb.x);
  float w0 = exp2f(ma.x - Ma), w1 = exp2f(mb.x - Ma);

  // store-row denominators (rows ibase + lhi*4 + r)
  float rden[4];
#pragma unroll
  for (int r = 0; r < 4; ++r) {
    int is = ibase + lhi * 4 + r;
    float2 s0 = ml0b[is], s1 = ml1b[is];
    float Ms = fmaxf(s0.x, s1.x);
    rden[r] = 1.0f / (s0.y * exp2f(s0.x - Ms) + s1.y * exp2f(s1.x - Ms));
  }

  floatx4 acc[16];
#pragma unroll
  for (int i = 0; i < 16; ++i) acc[i] = (floatx4){0.f, 0.f, 0.f, 0.f};

#pragma unroll
  for (int ks = 0; ks < 8; ++ks) {
    short8 o0 = *(const short8*)(c0base + (size_t)ia * C_DIM + ks * 32 + lhi * 8);
    short8 o1 = *(const short8*)(c1base + (size_t)ia * C_DIM + ks * 32 + lhi * 8);
    short8 am;
#pragma unroll
    for (int e = 0; e < 8; ++e)
      am[e] = (short)f2bf(w0 * bf2f((unsigned short)o0[e]) +
                          w1 * bf2f((unsigned short)o1[e]));
#pragma unroll
    for (int ob = 0; ob < 16; ++ob) {
      short8 bw = *(const short8*)(Wb + (size_t)(ob * 16 + l15) * C_DIM + ks * 32 + lhi * 8);
      acc[ob] = mfma16(am, bw, acc[ob]);
    }
  }
  float* outb = out + (size_t)b * C_DIM * N_TOK;
#pragma unroll
  for (int ob = 0; ob < 16; ++ob) {
#pragma unroll
    for (int r = 0; r < 4; ++r) {
      int o = ob * 16 + l15;
      int i = ibase + lhi * 4 + r;
      outb[(size_t)o * N_TOK + i] = acc[ob][r] * rden[r];
    }
  }
}

extern "C" void kernel_launch(void* const* d_in, const int* in_sizes, int n_in,
                              void* d_out, int out_size, void* d_ws, size_t ws_size,
                              hipStream_t stream) {
  const float* x = (const float*)d_in[0];
  const float* W = (const float*)d_in[1];
  float* out = (float*)d_out;
  char* ws = (char*)d_ws;
  const size_t SZ8 = (size_t)8 * N_TOK * C_DIM;      // 8 MB fp8 tensor
  const size_t SZ = SZ8 * 2;                         // 16 MB bf16 tensor
  unsigned char* xT8 = (unsigned char*)(ws);
  unsigned short* xC = (unsigned short*)(ws + SZ8);
  unsigned short* ctxP = (unsigned short*)(ws + SZ8 + SZ);        // 32 MB (2 halves)
  unsigned short* Wb = (unsigned short*)(ws + SZ8 + 3 * SZ);      // 128 KB
  float2* MLd = (float2*)(ws + SZ8 + 3 * SZ + C_DIM * C_DIM * 2); // 512 KB

  hipLaunchKernelGGL(transpose_conv, dim3(N_TOK / 32, C_DIM / 32, 8), dim3(256), 0,
                     stream, x, xT8, xC);
  hipLaunchKernelGGL(wconv, dim3((C_DIM * C_DIM) / 256), dim3(256), 0, stream, W, Wb);
  hipLaunchKernelGGL(attn_kernel, dim3(512), dim3(256), 0, stream, xT8, xC, ctxP, MLd);
  hipLaunchKernelGGL(outgemm, dim3(512), dim3(256), 0, stream, ctxP, Wb, MLd, out);
}

// Round 16
// 150.244 us; speedup vs baseline: 1.1405x; 1.1405x over previous
//
#include <hip/hip_runtime.h>

// SelfAttention: x[8,256,64,64] fp32, W[256,256] fp32.
// R16 = R15 with the cvt_pk_fp8 builtin fixed (hi flag must be a literal ->
// template<bool HI>). Full-fp8 attention math (QK and PV via
// mfma_scale_32x32x64_f8f6f4), JT=64, exact diagonal correction:
//   - P quantized to fp8, l summed with quantized diagonal,
//   - V fp8 stored PERM-ordered in global (matches P's register k-order),
//   - out += w_g * p_diag_hat * resid_i (resid = V - dec(fp8(V)), bf16).
// 512 blocks = 8b x 32qt x 2 j-halves; 4 waves x 32 q-rows; NT=32 (JT=64).
// LDS: K fp8 16KB + V fp8 16KB, double-buffered = 64KB -> 2 blocks/CU.
// ws: xT8[b][N][C] fp8 | xC8p[b][C][Nperm] fp8 | resid[b][N][C] bf16 |
//     ctxP[2][b][N][C] bf16 | Wb bf16 | MLd float4[2][b][N]

typedef __attribute__((ext_vector_type(8))) short short8;
typedef __attribute__((ext_vector_type(4))) float floatx4;
typedef __attribute__((ext_vector_type(16))) float floatx16;
typedef __attribute__((ext_vector_type(4))) int intx4;
typedef __attribute__((ext_vector_type(8))) int intx8;

#define N_TOK 4096
#define C_DIM 256
#define JT 64
#define NT 32  // 2048 / JT per half

typedef const __attribute__((address_space(1))) unsigned int g_uint;
typedef __attribute__((address_space(3))) unsigned int lds_uint;

__device__ __forceinline__ void gll16(const void* g, void* l) {
  __builtin_amdgcn_global_load_lds((g_uint*)g, (lds_uint*)l, 16, 0, 0);
}

__device__ __forceinline__ unsigned short f2bf(float f) {
  unsigned int u = __builtin_bit_cast(unsigned int, f);
  u += 0x7fffu + ((u >> 16) & 1u);
  return (unsigned short)(u >> 16);
}
__device__ __forceinline__ float bf2f(unsigned short v) {
  return __builtin_bit_cast(float, (unsigned int)v << 16);
}
// f32 -> fp8 e4m3fn, RNE, flush-subnormal, clamp 448
__device__ __forceinline__ unsigned char f2f8(float f) {
  unsigned u = __builtin_bit_cast(unsigned, f);
  unsigned sgn = (u >> 24) & 0x80u;
  unsigned a = u & 0x7fffffffu;
  if (a > 0x43e40000u) return (unsigned char)(sgn | 0x7e);
  unsigned lsb = (a >> 20) & 1u;
  a += 0x0007ffffu + lsb;
  int e = (int)(a >> 23) - 127;
  if (e < -6) return (unsigned char)sgn;
  if (e > 8) return (unsigned char)(sgn | 0x7e);
  unsigned m = (a >> 20) & 7u;
  return (unsigned char)(sgn | ((unsigned)(e + 7) << 3) | m);
}
// fp8 e4m3fn -> f32
__device__ __forceinline__ float f8dec(unsigned b) {
  unsigned s = (b & 0x80u) << 24;
  unsigned e = (b >> 3) & 15u;
  unsigned m = b & 7u;
  if (e)
    return __builtin_bit_cast(float, s | ((e + 120u) << 23) | (m << 20));
  float sub = (float)m * 0.001953125f;  // m/8 * 2^-6
  return (b & 0x80u) ? -sub : sub;
}

__device__ __forceinline__ floatx4 mfma16(short8 a, short8 b, floatx4 c) {
  return __builtin_amdgcn_mfma_f32_16x16x32_bf16(a, b, c, 0, 0, 0);
}
__device__ __forceinline__ floatx16 mfma8(intx8 a, intx8 b, floatx16 c) {
  // fp8 e4m3 A/B (cbsz=0, blgp=0), unity block scales
  return __builtin_amdgcn_mfma_scale_f32_32x32x64_f8f6f4(
      a, b, c, 0, 0, 0, 0x7f7f7f7f, 0, 0x7f7f7f7f);
}
template <bool HI>
__device__ __forceinline__ int pk_fp8(float a, float b, int old) {
#if __has_builtin(__builtin_amdgcn_cvt_pk_fp8_f32)
  return __builtin_amdgcn_cvt_pk_fp8_f32(a, b, old, HI);  // HI is a literal
#else
  unsigned w = (unsigned)f2f8(a) | ((unsigned)f2f8(b) << 8);
  return HI ? (int)(((unsigned)old & 0x0000ffffu) | (w << 16))
            : (int)(((unsigned)old & 0xffff0000u) | w);
#endif
}
__device__ __forceinline__ float sel4(float a, float b, float c, float d, int k) {
  float x = (k & 1) ? b : a;
  float y = (k & 1) ? d : c;
  return (k & 2) ? y : x;
}
__device__ __forceinline__ int sel4i(int a, int b, int c, int d, int k) {
  int x = (k & 1) ? b : a;
  int y = (k & 1) ? d : c;
  return (k & 2) ? y : x;
}

// perm: register k-byte kappa <-> logical j within a 64-j group.
// j(kappa) = u*32 + (r&3) + 8*((r>>2)&3) + 4h, h=kappa>>5,u=(kappa>>4)&1,r=kappa&15
// kappa(j) = ((j>>2)&1)*32 + ((j>>5)&1)*16 + ((j>>3)&3)*4 + (j&3)

// ---- K1a: x -> xT8[i][c] fp8, resid[i][c] bf16, xC8p[c][j-perm] fp8 ----
__global__ __launch_bounds__(256) void transpose_conv(
    const float* __restrict__ x, unsigned char* __restrict__ xT8,
    unsigned char* __restrict__ xC8p, unsigned short* __restrict__ resid) {
  __shared__ float tile[32][33];
  const int b = blockIdx.z;
  const int i0 = blockIdx.x * 32, c0 = blockIdx.y * 32;
  const int tx = threadIdx.x & 31, ty = threadIdx.x >> 5;
  const float* xb = x + (size_t)b * C_DIM * N_TOK;
#pragma unroll
  for (int p = 0; p < 4; ++p) {
    int c = c0 + ty + p * 8;
    float v = xb[(size_t)c * N_TOK + i0 + tx];
    tile[ty + p * 8][tx] = v;
    int j = i0 + tx, jg = j & 63;
    int kp = ((jg >> 2) & 1) * 32 + ((jg >> 5) & 1) * 16 + ((jg >> 3) & 3) * 4 + (jg & 3);
    xC8p[((size_t)b * C_DIM + c) * N_TOK + (j & ~63) + kp] = f2f8(v);
  }
  __syncthreads();
#pragma unroll
  for (int p = 0; p < 4; ++p) {
    int i = i0 + ty + p * 8;
    float v = tile[tx][ty + p * 8];
    unsigned char q8 = f2f8(v);
    size_t idx = ((size_t)b * N_TOK + i) * C_DIM + c0 + tx;
    xT8[idx] = q8;
    resid[idx] = f2bf(v - f8dec(q8));
  }
}

// ---- K1b: W fp32 -> bf16 ----
__global__ __launch_bounds__(256) void wconv(const float* __restrict__ W,
                                             unsigned short* __restrict__ Wb) {
  int idx = blockIdx.x * 256 + threadIdx.x;
  Wb[idx] = f2bf(W[idx]);
}

// ---- K2: split-K flash attention, full fp8. grid 512, 256 thr ----
// LDS buffer (32KB each, x2):
//   K fp8 [0,16KB):  64 rows x 256B, elem(j,c16) at j*256 + ((c16^(j&15))<<4)
//   V fp8 [16KB,32KB): 256 rows x 64B (kappa-slots), row c chunk k at
//       c*64 + ((k ^ ((c>>1)&3))<<4)  -- chunk k covers kappa 16k..16k+15
__global__ __launch_bounds__(256, 2) void attn_kernel(
    const unsigned char* __restrict__ xT8, const unsigned char* __restrict__ xC8p,
    unsigned short* __restrict__ ctxP, float4* __restrict__ MLd) {
  const int bid = blockIdx.x;
  const int b = bid & 7;           // batch == XCD -> L2 locality
  const int qt = (bid >> 3) & 31;  // q-tile (128 rows)
  const int g = bid >> 8;          // j-half
  const int tid = threadIdx.x;
  const int lane = tid & 63;
  const int wv = tid >> 6;
  const int l31 = lane & 31;
  const int h = lane >> 5;
  const unsigned char* xT8b = xT8 + (size_t)b * N_TOK * C_DIM;
  const unsigned char* xCb = xC8p + (size_t)b * C_DIM * N_TOK;
  const int qb = qt * 128 + wv * 32;

  __shared__ char lds[2][32768];

  // staging bases (inverse-swizzled, rule #21); i-step folds to immediates
  const char* kBase;
  {
    int j0 = wv * 4 + (lane >> 4);
    int c16 = (lane & 15) ^ (j0 & 15);
    kBase = (const char*)xT8b + (size_t)g * 2048 * 256 + j0 * 256 + c16 * 16;
  }
  const char* vBase;
  {
    int c0 = wv * 16 + (lane >> 2);
    int kv = (lane & 3) ^ ((lane >> 3) & 3);  // logical chunk at this slot
    vBase = (const char*)xCb + (size_t)c0 * N_TOK + g * 2048 + kv * 16;
  }
  auto STAGE_K = [&](int t, int sel) {
    char* Kd = lds[sel] + wv * 1024;
    const char* src = kBase + (size_t)t * 16384;
#pragma unroll
    for (int i = 0; i < 4; ++i) gll16(src + i * 4096, Kd + i * 4096);
  };
  auto STAGE_V = [&](int t, int sel) {
    char* Vd = lds[sel] + 16384 + wv * 1024;
    const char* src = vBase + (size_t)t * 64;
#pragma unroll
    for (int i = 0; i < 4; ++i) gll16(src + (size_t)i * 64 * N_TOK, Vd + i * 4096);
  };

  // Q fp8 B-fragments: row qb+l31, k-bytes c = ks*64 + h*32 + [0,32)
  intx8 q[4];
  {
    const unsigned char* qp = xT8b + (size_t)(qb + l31) * C_DIM + h * 32;
#pragma unroll
    for (int ks = 0; ks < 4; ++ks) {
      intx4 lo = *(const intx4*)(qp + ks * 64);
      intx4 hi = *(const intx4*)(qp + ks * 64 + 16);
      q[ks] = (intx8){lo.x, lo.y, lo.z, lo.w, hi.x, hi.y, hi.z, hi.w};
    }
  }

  // PV V-read offset (c = ct*32 + l31): a0 = l31*64 + ((2h ^ ((l31>>1)&3))<<4)
  const int a0 = l31 * 64 + (((2 * h) ^ ((l31 >> 1) & 3)) << 4);

  // diagonal bookkeeping
  const int tdiag = ((qb >> 11) == g) ? ((qb & 2047) >> 6) : -1;
  const int ud = (qb >> 5) & 1;          // which s-half holds the diagonal
  const int h_o = (l31 >> 2) & 1;        // which h-lane holds row l31's diag
  float pd_row = 0.f;

  floatx16 acc[8];
#pragma unroll
  for (int ct = 0; ct < 8; ++ct)
#pragma unroll
    for (int r = 0; r < 16; ++r) acc[ct][r] = 0.f;
  float m = -1e30f, lsum = 0.f;
  const float SC = 0.09016844005556021f;  // log2(e)/16

  STAGE_K(0, 0);
  STAGE_V(0, 0);

  for (int t = 0; t < NT; ++t) {
    __syncthreads();  // tile t staged (vmcnt drain); prev-buf reads done
    if (t + 1 < NT) {
      STAGE_K(t + 1, (t + 1) & 1);
      STAGE_V(t + 1, (t + 1) & 1);
    }
    const char* Kb = lds[t & 1];
    const char* Vb = lds[t & 1] + 16384;

    // S^T = mfma_scale(K8, Q8): s0 = j 0..31 (rows l31), s1 = j 32..63
    floatx16 s0, s1;
#pragma unroll
    for (int r = 0; r < 16; ++r) { s0[r] = 0.f; s1[r] = 0.f; }
    __builtin_amdgcn_s_setprio(1);
#pragma unroll
    for (int ks = 0; ks < 4; ++ks) {
      int ch = ((ks * 4 + h * 2) ^ (l31 & 15)) << 4;
      intx4 ka = *(const intx4*)(Kb + l31 * 256 + ch);
      intx4 kb2 = *(const intx4*)(Kb + l31 * 256 + (ch ^ 16));
      intx8 kf = (intx8){ka.x, ka.y, ka.z, ka.w, kb2.x, kb2.y, kb2.z, kb2.w};
      s0 = mfma8(kf, q[ks], s0);
      ka = *(const intx4*)(Kb + (32 + l31) * 256 + ch);
      kb2 = *(const intx4*)(Kb + (32 + l31) * 256 + (ch ^ 16));
      kf = (intx8){ka.x, ka.y, ka.z, ka.w, kb2.x, kb2.y, kb2.z, kb2.w};
      s1 = mfma8(kf, q[ks], s1);
    }
    __builtin_amdgcn_s_setprio(0);

    // online softmax over 64 j (lane holds 32; partner h-lane the rest)
    float mx = fmaxf(s0[0], s1[0]);
#pragma unroll
    for (int r = 1; r < 16; ++r) mx = fmaxf(mx, fmaxf(s0[r], s1[r]));
    mx = fmaxf(mx, __shfl_xor(mx, 32));
    float pm = mx * SC;
    bool need = __any(pm > m + 8.0f) != 0;  // defer-max (T13)
    float mn = need ? fmaxf(m, pm) : m;
    float al = need ? exp2f(m - mn) : 1.0f;
    m = mn;
    float rsum = 0.f;
#pragma unroll
    for (int r = 0; r < 16; ++r) {
      s0[r] = exp2f(s0[r] * SC - mn); rsum += s0[r];
      s1[r] = exp2f(s1[r] * SC - mn); rsum += s1[r];
    }

    // quantize P to fp8; pk[w] bytes = kappa 4w..4w+3 of this lane's window
    int pk[8];
#pragma unroll
    for (int i = 0; i < 4; ++i) {
      int v = pk_fp8<false>(s0[4 * i], s0[4 * i + 1], 0);
      pk[i] = pk_fp8<true>(s0[4 * i + 2], s0[4 * i + 3], v);
      v = pk_fp8<false>(s1[4 * i], s1[4 * i + 1], 0);
      pk[4 + i] = pk_fp8<true>(s1[4 * i + 2], s1[4 * i + 3], v);
    }

    if (t == tdiag) {  // wave-uniform; exact diagonal bookkeeping
      int k1 = l31 & 3, k2 = l31 >> 3;
      floatx16 sv = ud ? s1 : s0;
      float aa = sel4(sv[0], sv[1], sv[2], sv[3], k1);
      float bb = sel4(sv[4], sv[5], sv[6], sv[7], k1);
      float cc = sel4(sv[8], sv[9], sv[10], sv[11], k1);
      float dd = sel4(sv[12], sv[13], sv[14], sv[15], k1);
      float p_d = sel4(aa, bb, cc, dd, k2);
      int pw = ud ? sel4i(pk[4], pk[5], pk[6], pk[7], k2)
                  : sel4i(pk[0], pk[1], pk[2], pk[3], k2);
      float pq = f8dec((unsigned)(pw >> (8 * k1)) & 255u);
      bool mine = (h == h_o);
      rsum += mine ? (pq - p_d) : 0.f;  // l uses quantized diagonal
      float pdl = mine ? pq : 0.f;
      pdl += __shfl_xor(pdl, 32);
      pd_row = pdl;
    }
    rsum += __shfl_xor(rsum, 32);
    lsum = lsum * al + rsum;
    if (need) {  // wave-uniform, rare after warmup
#pragma unroll
      for (int r = 0; r < 16; ++r) {
        float ar = __shfl(al, (r & 3) + 8 * (r >> 2) + 4 * h);
#pragma unroll
        for (int ct = 0; ct < 8; ++ct) acc[ct][r] *= ar;
      }
    }

    // O[i][c] += P[i][j] V[j][c] : one fp8 mfma_scale per 32-c group
    intx8 pa = (intx8){pk[0], pk[1], pk[2], pk[3], pk[4], pk[5], pk[6], pk[7]};
    __builtin_amdgcn_s_setprio(1);
#pragma unroll
    for (int ct = 0; ct < 8; ++ct) {
      const char* vp = Vb + ct * 2048;
      intx4 lo = *(const intx4*)(vp + a0);
      intx4 hi = *(const intx4*)(vp + (a0 ^ 16));
      intx8 vf = (intx8){lo.x, lo.y, lo.z, lo.w, hi.x, hi.y, hi.z, hi.w};
      acc[ct] = mfma8(pa, vf, acc[ct]);
    }
    __builtin_amdgcn_s_setprio(0);
  }

  // epilogue: store partial O (bf16, unnormalized) + (m, l, p_diag)
  if (h == 0) {
    float4 ml;
    ml.x = m; ml.y = lsum; ml.z = pd_row; ml.w = 0.f;
    MLd[((size_t)g * 8 + b) * N_TOK + qb + l31] = ml;
  }
  unsigned short* cb = ctxP + (((size_t)g * 8 + b) * N_TOK + qb) * C_DIM;
#pragma unroll
  for (int r = 0; r < 16; ++r) {
    int ri = (r & 3) + 8 * (r >> 2) + 4 * h;
#pragma unroll
    for (int ct = 0; ct < 8; ++ct)
      cb[(size_t)ri * C_DIM + ct * 32 + l31] = f2bf(acc[ct][r]);
  }
}

// ---- K3: merge halves + diag-resid correction + out = W ctx / l ----
__global__ __launch_bounds__(256) void outgemm(
    const unsigned short* __restrict__ ctxP, const unsigned short* __restrict__ Wb,
    const float4* __restrict__ MLd, const unsigned short* __restrict__ resid,
    float* __restrict__ out) {
  const int bid = blockIdx.x;
  const int b = bid & 7;
  const int it = bid >> 3;
  const int lane = threadIdx.x & 63;
  const int w = threadIdx.x >> 6;
  const int ibase = it * 64 + w * 16;
  const int l15 = lane & 15, lhi = lane >> 4;
  const unsigned short* c0base = ctxP + (size_t)b * N_TOK * C_DIM;
  const unsigned short* c1base = ctxP + (size_t)(8 + b) * N_TOK * C_DIM;
  const float4* ml0b = MLd + (size_t)b * N_TOK;
  const float4* ml1b = MLd + (size_t)(8 + b) * N_TOK;

  // A-row merge weights + diag correction weight (row ia = ibase + l15)
  const int ia = ibase + l15;
  float4 ma = ml0b[ia], mb = ml1b[ia];
  float Ma = fmaxf(ma.x, mb.x);
  float w0 = exp2f(ma.x - Ma), w1 = exp2f(mb.x - Ma);
  float pda = w0 * ma.z + w1 * mb.z;
  const unsigned short* rrow = resid + (((size_t)b * N_TOK + ia) * C_DIM);

  // store-row denominators (rows ibase + lhi*4 + r)
  float rden[4];
#pragma unroll
  for (int r = 0; r < 4; ++r) {
    int is = ibase + lhi * 4 + r;
    float4 s0 = ml0b[is], s1 = ml1b[is];
    float Ms = fmaxf(s0.x, s1.x);
    rden[r] = 1.0f / (s0.y * exp2f(s0.x - Ms) + s1.y * exp2f(s1.x - Ms));
  }

  floatx4 acc[16];
#pragma unroll
  for (int i = 0; i < 16; ++i) acc[i] = (floatx4){0.f, 0.f, 0.f, 0.f};

#pragma unroll
  for (int ks = 0; ks < 8; ++ks) {
    short8 o0 = *(const short8*)(c0base + (size_t)ia * C_DIM + ks * 32 + lhi * 8);
    short8 o1 = *(const short8*)(c1base + (size_t)ia * C_DIM + ks * 32 + lhi * 8);
    short8 rs = *(const short8*)(rrow + ks * 32 + lhi * 8);
    short8 am;
#pragma unroll
    for (int e = 0; e < 8; ++e)
      am[e] = (short)f2bf(w0 * bf2f((unsigned short)o0[e]) +
                          w1 * bf2f((unsigned short)o1[e]) +
                          pda * bf2f((unsigned short)rs[e]));
#pragma unroll
    for (int ob = 0; ob < 16; ++ob) {
      short8 bw = *(const short8*)(Wb + (size_t)(ob * 16 + l15) * C_DIM + ks * 32 + lhi * 8);
      acc[ob] = mfma16(am, bw, acc[ob]);
    }
  }
  float* outb = out + (size_t)b * C_DIM * N_TOK;
#pragma unroll
  for (int ob = 0; ob < 16; ++ob) {
#pragma unroll
    for (int r = 0; r < 4; ++r) {
      int o = ob * 16 + l15;
      int i = ibase + lhi * 4 + r;
      outb[(size_t)o * N_TOK + i] = acc[ob][r] * rden[r];
    }
  }
}

extern "C" void kernel_launch(void* const* d_in, const int* in_sizes, int n_in,
                              void* d_out, int out_size, void* d_ws, size_t ws_size,
                              hipStream_t stream) {
  const float* x = (const float*)d_in[0];
  const float* W = (const float*)d_in[1];
  float* out = (float*)d_out;
  char* ws = (char*)d_ws;
  const size_t SZ8 = (size_t)8 * N_TOK * C_DIM;      // 8 MB fp8 tensor
  const size_t SZ = SZ8 * 2;                         // 16 MB bf16 tensor
  unsigned char* xT8 = (unsigned char*)(ws);                       // 8 MB
  unsigned char* xC8p = (unsigned char*)(ws + SZ8);                // 8 MB
  unsigned short* resid = (unsigned short*)(ws + 2 * SZ8);         // 16 MB
  unsigned short* ctxP = (unsigned short*)(ws + 2 * SZ8 + SZ);     // 32 MB
  unsigned short* Wb = (unsigned short*)(ws + 2 * SZ8 + 3 * SZ);   // 128 KB
  float4* MLd = (float4*)(ws + 2 * SZ8 + 3 * SZ + C_DIM * C_DIM * 2);  // 1 MB

  hipLaunchKernelGGL(transpose_conv, dim3(N_TOK / 32, C_DIM / 32, 8), dim3(256), 0,
                     stream, x, xT8, xC8p, resid);
  hipLaunchKernelGGL(wconv, dim3((C_DIM * C_DIM) / 256), dim3(256), 0, stream, W, Wb);
  hipLaunchKernelGGL(attn_kernel, dim3(512), dim3(256), 0, stream, xT8, xC8p, ctxP, MLd);
  hipLaunchKernelGGL(outgemm, dim3(512), dim3(256), 0, stream, ctxP, Wb, MLd, resid, out);
}

// Round 17
// 144.868 us; speedup vs baseline: 1.1828x; 1.0371x over previous
//
#include <hip/hip_runtime.h>

// SelfAttention: x[8,256,64,64] fp32, W[256,256] fp32.
// R17 = R16 (full-fp8 QK+PV, JT=64, diag-resid correction) with PER-ROW
// STATIC softmax shift m_i = |x8_i|^2 * SC (precomputed from the SAME fp8
// values the MFMA consumes -> P_diag == 1.0 exactly):
//   - no online max, no alpha rescale, no per-iter shuffles, no diag
//     bookkeeping in-kernel (pd == 1.0 const; l patch is O(1e-5), dropped),
//   - overflow-safe: P <= exp2(|x_i|(|x_j|-|x_i|)SC) <= 223 < 448 (C-S bound),
//   - flushed off-diag terms (~2^-21) were already flushed in R16 (passed).
// 512 blocks = 8b x 32qt x 2 j-halves; 4 waves x 32 q-rows; NT=32 (JT=64).
// LDS: K fp8 16KB + V fp8 16KB, double-buffered = 64KB -> 2 blocks/CU.
// ws: xT8[b][N][C] fp8 | xC8p[b][C][Nperm] fp8 | resid[b][N][C] bf16 |
//     ctxP[2][b][N][C] bf16 | Wb bf16 | Ld float[2][b][N] | Mrow float[b][N]

typedef __attribute__((ext_vector_type(8))) short short8;
typedef __attribute__((ext_vector_type(4))) float floatx4;
typedef __attribute__((ext_vector_type(16))) float floatx16;
typedef __attribute__((ext_vector_type(4))) int intx4;
typedef __attribute__((ext_vector_type(8))) int intx8;

#define N_TOK 4096
#define C_DIM 256
#define JT 64
#define NT 32  // 2048 / JT per half
#define SC 0.09016844005556021f  // log2(e)/16

typedef const __attribute__((address_space(1))) unsigned int g_uint;
typedef __attribute__((address_space(3))) unsigned int lds_uint;

__device__ __forceinline__ void gll16(const void* g, void* l) {
  __builtin_amdgcn_global_load_lds((g_uint*)g, (lds_uint*)l, 16, 0, 0);
}

__device__ __forceinline__ unsigned short f2bf(float f) {
  unsigned int u = __builtin_bit_cast(unsigned int, f);
  u += 0x7fffu + ((u >> 16) & 1u);
  return (unsigned short)(u >> 16);
}
__device__ __forceinline__ float bf2f(unsigned short v) {
  return __builtin_bit_cast(float, (unsigned int)v << 16);
}
// f32 -> fp8 e4m3fn, RNE, flush-subnormal, clamp 448
__device__ __forceinline__ unsigned char f2f8(float f) {
  unsigned u = __builtin_bit_cast(unsigned, f);
  unsigned sgn = (u >> 24) & 0x80u;
  unsigned a = u & 0x7fffffffu;
  if (a > 0x43e40000u) return (unsigned char)(sgn | 0x7e);
  unsigned lsb = (a >> 20) & 1u;
  a += 0x0007ffffu + lsb;
  int e = (int)(a >> 23) - 127;
  if (e < -6) return (unsigned char)sgn;
  if (e > 8) return (unsigned char)(sgn | 0x7e);
  unsigned m = (a >> 20) & 7u;
  return (unsigned char)(sgn | ((unsigned)(e + 7) << 3) | m);
}
// fp8 e4m3fn -> f32 (matches HW decode incl. subnormals)
__device__ __forceinline__ float f8dec(unsigned b) {
  unsigned s = (b & 0x80u) << 24;
  unsigned e = (b >> 3) & 15u;
  unsigned m = b & 7u;
  if (e)
    return __builtin_bit_cast(float, s | ((e + 120u) << 23) | (m << 20));
  float sub = (float)m * 0.001953125f;  // m * 2^-9
  return (b & 0x80u) ? -sub : sub;
}

__device__ __forceinline__ floatx4 mfma16(short8 a, short8 b, floatx4 c) {
  return __builtin_amdgcn_mfma_f32_16x16x32_bf16(a, b, c, 0, 0, 0);
}
__device__ __forceinline__ floatx16 mfma8(intx8 a, intx8 b, floatx16 c) {
  // fp8 e4m3 A/B (cbsz=0, blgp=0), unity block scales
  return __builtin_amdgcn_mfma_scale_f32_32x32x64_f8f6f4(
      a, b, c, 0, 0, 0, 0x7f7f7f7f, 0, 0x7f7f7f7f);
}
template <bool HI>
__device__ __forceinline__ int pk_fp8(float a, float b, int old) {
#if __has_builtin(__builtin_amdgcn_cvt_pk_fp8_f32)
  return __builtin_amdgcn_cvt_pk_fp8_f32(a, b, old, HI);  // HI is a literal
#else
  unsigned w = (unsigned)f2f8(a) | ((unsigned)f2f8(b) << 8);
  return HI ? (int)(((unsigned)old & 0x0000ffffu) | (w << 16))
            : (int)(((unsigned)old & 0xffff0000u) | w);
#endif
}

// perm: register k-byte kappa <-> logical j within a 64-j group.
// kappa(j) = ((j>>2)&1)*32 + ((j>>5)&1)*16 + ((j>>3)&3)*4 + (j&3)

// ---- K1a: x -> xT8[i][c] fp8, resid[i][c] bf16, xC8p[c][j-perm] fp8 ----
__global__ __launch_bounds__(256) void transpose_conv(
    const float* __restrict__ x, unsigned char* __restrict__ xT8,
    unsigned char* __restrict__ xC8p, unsigned short* __restrict__ resid) {
  __shared__ float tile[32][33];
  const int b = blockIdx.z;
  const int i0 = blockIdx.x * 32, c0 = blockIdx.y * 32;
  const int tx = threadIdx.x & 31, ty = threadIdx.x >> 5;
  const float* xb = x + (size_t)b * C_DIM * N_TOK;
#pragma unroll
  for (int p = 0; p < 4; ++p) {
    int c = c0 + ty + p * 8;
    float v = xb[(size_t)c * N_TOK + i0 + tx];
    tile[ty + p * 8][tx] = v;
    int j = i0 + tx, jg = j & 63;
    int kp = ((jg >> 2) & 1) * 32 + ((jg >> 5) & 1) * 16 + ((jg >> 3) & 3) * 4 + (jg & 3);
    xC8p[((size_t)b * C_DIM + c) * N_TOK + (j & ~63) + kp] = f2f8(v);
  }
  __syncthreads();
#pragma unroll
  for (int p = 0; p < 4; ++p) {
    int i = i0 + ty + p * 8;
    float v = tile[tx][ty + p * 8];
    unsigned char q8 = f2f8(v);
    size_t idx = ((size_t)b * N_TOK + i) * C_DIM + c0 + tx;
    xT8[idx] = q8;
    resid[idx] = f2bf(v - f8dec(q8));
  }
}

// ---- K1b: W fp32 -> bf16 ----
__global__ __launch_bounds__(256) void wconv(const float* __restrict__ W,
                                             unsigned short* __restrict__ Wb) {
  int idx = blockIdx.x * 256 + threadIdx.x;
  Wb[idx] = f2bf(W[idx]);
}

// ---- K1c: Mrow[row] = SC * sum_c dec(xT8[row][c])^2 (one wave per row) ----
__global__ __launch_bounds__(256) void mrow_kernel(
    const unsigned char* __restrict__ xT8, float* __restrict__ Mrow) {
  const int row = blockIdx.x * 4 + (threadIdx.x >> 6);
  const int lane = threadIdx.x & 63;
  const unsigned char* rp = xT8 + (size_t)row * C_DIM + lane * 4;
  float s = 0.f;
#pragma unroll
  for (int e = 0; e < 4; ++e) {
    float v = f8dec(rp[e]);
    s += v * v;
  }
  s += __shfl_xor(s, 1);
  s += __shfl_xor(s, 2);
  s += __shfl_xor(s, 4);
  s += __shfl_xor(s, 8);
  s += __shfl_xor(s, 16);
  s += __shfl_xor(s, 32);
  if (lane == 0) Mrow[row] = s * SC;
}

// ---- K2: split-K flash attention, full fp8, static per-row shift ----
// LDS buffer (32KB each, x2):
//   K fp8 [0,16KB):  64 rows x 256B, elem(j,c16) at j*256 + ((c16^(j&15))<<4)
//   V fp8 [16KB,32KB): 256 rows x 64B (kappa-slots), row c chunk k at
//       c*64 + ((k ^ ((c>>1)&3))<<4)
__global__ __launch_bounds__(256, 2) void attn_kernel(
    const unsigned char* __restrict__ xT8, const unsigned char* __restrict__ xC8p,
    const float* __restrict__ Mrow, unsigned short* __restrict__ ctxP,
    float* __restrict__ Ld) {
  const int bid = blockIdx.x;
  const int b = bid & 7;           // batch == XCD -> L2 locality
  const int qt = (bid >> 3) & 31;  // q-tile (128 rows)
  const int g = bid >> 8;          // j-half
  const int tid = threadIdx.x;
  const int lane = tid & 63;
  const int wv = tid >> 6;
  const int l31 = lane & 31;
  const int h = lane >> 5;
  const unsigned char* xT8b = xT8 + (size_t)b * N_TOK * C_DIM;
  const unsigned char* xCb = xC8p + (size_t)b * C_DIM * N_TOK;
  const int qb = qt * 128 + wv * 32;

  __shared__ char lds[2][32768];

  // staging bases (inverse-swizzled, rule #21); i-step folds to immediates
  const char* kBase;
  {
    int j0 = wv * 4 + (lane >> 4);
    int c16 = (lane & 15) ^ (j0 & 15);
    kBase = (const char*)xT8b + (size_t)g * 2048 * 256 + j0 * 256 + c16 * 16;
  }
  const char* vBase;
  {
    int c0 = wv * 16 + (lane >> 2);
    int kv = (lane & 3) ^ ((lane >> 3) & 3);
    vBase = (const char*)xCb + (size_t)c0 * N_TOK + g * 2048 + kv * 16;
  }
  auto STAGE_K = [&](int t, int sel) {
    char* Kd = lds[sel] + wv * 1024;
    const char* src = kBase + (size_t)t * 16384;
#pragma unroll
    for (int i = 0; i < 4; ++i) gll16(src + i * 4096, Kd + i * 4096);
  };
  auto STAGE_V = [&](int t, int sel) {
    char* Vd = lds[sel] + 16384 + wv * 1024;
    const char* src = vBase + (size_t)t * 64;
#pragma unroll
    for (int i = 0; i < 4; ++i) gll16(src + (size_t)i * 64 * N_TOK, Vd + i * 4096);
  };

  // Q fp8 B-fragments: row qb+l31, k-bytes c = ks*64 + h*32 + [0,32)
  intx8 q[4];
  {
    const unsigned char* qp = xT8b + (size_t)(qb + l31) * C_DIM + h * 32;
#pragma unroll
    for (int ks = 0; ks < 4; ++ks) {
      intx4 lo = *(const intx4*)(qp + ks * 64);
      intx4 hi = *(const intx4*)(qp + ks * 64 + 16);
      q[ks] = (intx8){lo.x, lo.y, lo.z, lo.w, hi.x, hi.y, hi.z, hi.w};
    }
  }
  // static per-row shift (all of this lane's s values belong to q-row l31)
  const float mi = Mrow[(size_t)b * N_TOK + qb + l31];

  // PV V-read offset (c = ct*32 + l31)
  const int a0 = l31 * 64 + (((2 * h) ^ ((l31 >> 1) & 3)) << 4);

  floatx16 acc[8];
#pragma unroll
  for (int ct = 0; ct < 8; ++ct)
#pragma unroll
    for (int r = 0; r < 16; ++r) acc[ct][r] = 0.f;
  float lsum = 0.f;

  STAGE_K(0, 0);
  STAGE_V(0, 0);

  for (int t = 0; t < NT; ++t) {
    __syncthreads();  // tile t staged (vmcnt drain); prev-buf reads done
    if (t + 1 < NT) {
      STAGE_K(t + 1, (t + 1) & 1);
      STAGE_V(t + 1, (t + 1) & 1);
    }
    const char* Kb = lds[t & 1];
    const char* Vb = lds[t & 1] + 16384;

    // S^T = mfma_scale(K8, Q8): s0 = j 0..31, s1 = j 32..63
    floatx16 s0, s1;
#pragma unroll
    for (int r = 0; r < 16; ++r) { s0[r] = 0.f; s1[r] = 0.f; }
    __builtin_amdgcn_s_setprio(1);
#pragma unroll
    for (int ks = 0; ks < 4; ++ks) {
      int ch = ((ks * 4 + h * 2) ^ (l31 & 15)) << 4;
      intx4 ka = *(const intx4*)(Kb + l31 * 256 + ch);
      intx4 kb2 = *(const intx4*)(Kb + l31 * 256 + (ch ^ 16));
      intx8 kf = (intx8){ka.x, ka.y, ka.z, ka.w, kb2.x, kb2.y, kb2.z, kb2.w};
      s0 = mfma8(kf, q[ks], s0);
      ka = *(const intx4*)(Kb + (32 + l31) * 256 + ch);
      kb2 = *(const intx4*)(Kb + (32 + l31) * 256 + (ch ^ 16));
      kf = (intx8){ka.x, ka.y, ka.z, ka.w, kb2.x, kb2.y, kb2.z, kb2.w};
      s1 = mfma8(kf, q[ks], s1);
    }
    __builtin_amdgcn_s_setprio(0);

    // static-shift softmax: pure per-lane (no max scan, no shuffles)
#pragma unroll
    for (int r = 0; r < 16; ++r) {
      s0[r] = exp2f(s0[r] * SC - mi);
      s1[r] = exp2f(s1[r] * SC - mi);
      lsum += s0[r] + s1[r];
    }

    // quantize P to fp8
    int pk[8];
#pragma unroll
    for (int i = 0; i < 4; ++i) {
      int v = pk_fp8<false>(s0[4 * i], s0[4 * i + 1], 0);
      pk[i] = pk_fp8<true>(s0[4 * i + 2], s0[4 * i + 3], v);
      v = pk_fp8<false>(s1[4 * i], s1[4 * i + 1], 0);
      pk[4 + i] = pk_fp8<true>(s1[4 * i + 2], s1[4 * i + 3], v);
    }

    // O[i][c] += P[i][j] V[j][c] : one fp8 mfma_scale per 32-c group
    intx8 pa = (intx8){pk[0], pk[1], pk[2], pk[3], pk[4], pk[5], pk[6], pk[7]};
    __builtin_amdgcn_s_setprio(1);
#pragma unroll
    for (int ct = 0; ct < 8; ++ct) {
      const char* vp = Vb + ct * 2048;
      intx4 lo = *(const intx4*)(vp + a0);
      intx4 hi = *(const intx4*)(vp + (a0 ^ 16));
      intx8 vf = (intx8){lo.x, lo.y, lo.z, lo.w, hi.x, hi.y, hi.z, hi.w};
      acc[ct] = mfma8(pa, vf, acc[ct]);
    }
    __builtin_amdgcn_s_setprio(0);
  }

  // epilogue: store partial O (bf16, unnormalized) + l
  lsum += __shfl_xor(lsum, 32);
  if (h == 0) Ld[((size_t)g * 8 + b) * N_TOK + qb + l31] = lsum;
  unsigned short* cb = ctxP + (((size_t)g * 8 + b) * N_TOK + qb) * C_DIM;
#pragma unroll
  for (int r = 0; r < 16; ++r) {
    int ri = (r & 3) + 8 * (r >> 2) + 4 * h;
#pragma unroll
    for (int ct = 0; ct < 8; ++ct)
      cb[(size_t)ri * C_DIM + ct * 32 + l31] = f2bf(acc[ct][r]);
  }
}

// ---- K3: merge halves + diag-resid correction (pd == 1) + out = W ctx / l ----
__global__ __launch_bounds__(256) void outgemm(
    const unsigned short* __restrict__ ctxP, const unsigned short* __restrict__ Wb,
    const float* __restrict__ Ld, const unsigned short* __restrict__ resid,
    float* __restrict__ out) {
  const int bid = blockIdx.x;
  const int b = bid & 7;
  const int it = bid >> 3;
  const int lane = threadIdx.x & 63;
  const int w = threadIdx.x >> 6;
  const int ibase = it * 64 + w * 16;
  const int l15 = lane & 15, lhi = lane >> 4;
  const unsigned short* c0base = ctxP + (size_t)b * N_TOK * C_DIM;
  const unsigned short* c1base = ctxP + (size_t)(8 + b) * N_TOK * C_DIM;
  const float* l0b = Ld + (size_t)b * N_TOK;
  const float* l1b = Ld + (size_t)(8 + b) * N_TOK;

  const int ia = ibase + l15;
  const unsigned short* rrow = resid + (((size_t)b * N_TOK + ia) * C_DIM);

  // store-row denominators (rows ibase + lhi*4 + r)
  float rden[4];
#pragma unroll
  for (int r = 0; r < 4; ++r) {
    int is = ibase + lhi * 4 + r;
    rden[r] = 1.0f / (l0b[is] + l1b[is]);
  }

  floatx4 acc[16];
#pragma unroll
  for (int i = 0; i < 16; ++i) acc[i] = (floatx4){0.f, 0.f, 0.f, 0.f};

#pragma unroll
  for (int ks = 0; ks < 8; ++ks) {
    short8 o0 = *(const short8*)(c0base + (size_t)ia * C_DIM + ks * 32 + lhi * 8);
    short8 o1 = *(const short8*)(c1base + (size_t)ia * C_DIM + ks * 32 + lhi * 8);
    short8 rs = *(const short8*)(rrow + ks * 32 + lhi * 8);
    short8 am;
#pragma unroll
    for (int e = 0; e < 8; ++e)
      am[e] = (short)f2bf(bf2f((unsigned short)o0[e]) +
                          bf2f((unsigned short)o1[e]) +
                          bf2f((unsigned short)rs[e]));
#pragma unroll
    for (int ob = 0; ob < 16; ++ob) {
      short8 bw = *(const short8*)(Wb + (size_t)(ob * 16 + l15) * C_DIM + ks * 32 + lhi * 8);
      acc[ob] = mfma16(am, bw, acc[ob]);
    }
  }
  float* outb = out + (size_t)b * C_DIM * N_TOK;
#pragma unroll
  for (int ob = 0; ob < 16; ++ob) {
#pragma unroll
    for (int r = 0; r < 4; ++r) {
      int o = ob * 16 + l15;
      int i = ibase + lhi * 4 + r;
      outb[(size_t)o * N_TOK + i] = acc[ob][r] * rden[r];
    }
  }
}

extern "C" void kernel_launch(void* const* d_in, const int* in_sizes, int n_in,
                              void* d_out, int out_size, void* d_ws, size_t ws_size,
                              hipStream_t stream) {
  const float* x = (const float*)d_in[0];
  const float* W = (const float*)d_in[1];
  float* out = (float*)d_out;
  char* ws = (char*)d_ws;
  const size_t SZ8 = (size_t)8 * N_TOK * C_DIM;      // 8 MB fp8 tensor
  const size_t SZ = SZ8 * 2;                         // 16 MB bf16 tensor
  unsigned char* xT8 = (unsigned char*)(ws);                       // 8 MB
  unsigned char* xC8p = (unsigned char*)(ws + SZ8);                // 8 MB
  unsigned short* resid = (unsigned short*)(ws + 2 * SZ8);         // 16 MB
  unsigned short* ctxP = (unsigned short*)(ws + 2 * SZ8 + SZ);     // 32 MB
  unsigned short* Wb = (unsigned short*)(ws + 2 * SZ8 + 3 * SZ);   // 128 KB
  float* Ld = (float*)(ws + 2 * SZ8 + 3 * SZ + C_DIM * C_DIM * 2);       // 256 KB
  float* Mrow = (float*)(ws + 2 * SZ8 + 3 * SZ + C_DIM * C_DIM * 2 + 262144);  // 128 KB

  hipLaunchKernelGGL(transpose_conv, dim3(N_TOK / 32, C_DIM / 32, 8), dim3(256), 0,
                     stream, x, xT8, xC8p, resid);
  hipLaunchKernelGGL(wconv, dim3((C_DIM * C_DIM) / 256), dim3(256), 0, stream, W, Wb);
  hipLaunchKernelGGL(mrow_kernel, dim3(8 * N_TOK / 4), dim3(256), 0, stream, xT8, Mrow);
  hipLaunchKernelGGL(attn_kernel, dim3(512), dim3(256), 0, stream, xT8, xC8p, Mrow,
                     ctxP, Ld);
  hipLaunchKernelGGL(outgemm, dim3(512), dim3(256), 0, stream, ctxP, Wb, Ld, resid, out);
}